// Round 8
// baseline (835.039 us; speedup 1.0000x reference)
//
#include <hip/hip_runtime.h>

#define NN 8192
#define CAP 128          // max nnz per Laplacian row (mean ~34)
#define PLDA 68          // A LDS row stride (64+4 floats)
#define PLDB 72          // B LDS row stride (64+8 shorts)

typedef __attribute__((ext_vector_type(8))) short bf16x8;
typedef __attribute__((ext_vector_type(4))) float f32x4;

__device__ __forceinline__ short f2bf(float f) {
    unsigned u = __builtin_bit_cast(unsigned, f);
    u += 0x7FFFu + ((u >> 16) & 1u);          // round-to-nearest-even
    return (short)(u >> 16);
}

// ---------------- z = x @ W  (+ fused partial s,t for the attention convs)
// stP layout: sP[4][NN] then tP[4][NN]; wsel 0..3 = down_f0,down_f1,up_f0,up_f1
__global__ __launch_bounds__(256) void k_small_gemm(
        const float* __restrict__ x, const float* __restrict__ Wdown,
        const float* __restrict__ Wup, const float* __restrict__ Whar,
        const float* __restrict__ a_down, const float* __restrict__ a_up,
        float* __restrict__ zbuf, float* __restrict__ stP) {
    int wsel = blockIdx.y;
    const float* W = (wsel == 0) ? Wdown : (wsel == 1) ? Wdown + 16384 :
                     (wsel == 2) ? Wup   : (wsel == 3) ? Wup + 16384 : Whar;
    float* out = zbuf + (size_t)wsel * NN * 128;
    __shared__ float Wl[128 * 128];
    __shared__ float Xl[32 * 128];
    int tid = threadIdx.x;
    int row0 = blockIdx.x * 32;
    const float4* W4 = (const float4*)W;
    float4* Wl4 = (float4*)Wl;
    for (int i = tid; i < 4096; i += 256) Wl4[i] = W4[i];
    const float4* X4 = (const float4*)(x + (size_t)row0 * 128);
    float4* Xl4 = (float4*)Xl;
    for (int i = tid; i < 1024; i += 256) Xl4[i] = X4[i];
    __syncthreads();
    int tx = tid & 31, ty = tid >> 5;
    float acc[4][4] = {};
#pragma unroll 2
    for (int i = 0; i < 128; ++i) {
        float w0 = Wl[i * 128 + tx];
        float w1 = Wl[i * 128 + tx + 32];
        float w2 = Wl[i * 128 + tx + 64];
        float w3 = Wl[i * 128 + tx + 96];
#pragma unroll
        for (int rr = 0; rr < 4; ++rr) {
            float xv = Xl[(ty * 4 + rr) * 128 + i];
            acc[rr][0] += xv * w0; acc[rr][1] += xv * w1;
            acc[rr][2] += xv * w2; acc[rr][3] += xv * w3;
        }
    }
#pragma unroll
    for (int rr = 0; rr < 4; ++rr) {
        float* o = out + (size_t)(row0 + ty * 4 + rr) * 128 + tx;
        o[0] = acc[rr][0]; o[32] = acc[rr][1]; o[64] = acc[rr][2]; o[96] = acc[rr][3];
    }
    if (wsel < 4) {
        const float* a = (wsel < 2) ? a_down : a_up;
        int f = wsel & 1;
        float asv[4], atv[4];
#pragma unroll
        for (int q = 0; q < 4; ++q) {
            asv[q] = a[f * 128 + tx + q * 32];
            atv[q] = a[256 + f * 128 + tx + q * 32];
        }
#pragma unroll
        for (int rr = 0; rr < 4; ++rr) {
            float ps = acc[rr][0] * asv[0] + acc[rr][1] * asv[1]
                     + acc[rr][2] * asv[2] + acc[rr][3] * asv[3];
            float pt = acc[rr][0] * atv[0] + acc[rr][1] * atv[1]
                     + acc[rr][2] * atv[2] + acc[rr][3] * atv[3];
            for (int w = 16; w; w >>= 1) {
                ps += __shfl_xor(ps, w);
                pt += __shfl_xor(pt, w);
            }
            if (tx == 0) {
                int row = row0 + ty * 4 + rr;
                stP[(size_t)wsel * NN + row] = ps;
                stP[(size_t)(4 + wsel) * NN + row] = pt;
            }
        }
    }
}

// ---- fused: nonzero scan (depth-8 load pipeline) -> padded CSR + softmax
__global__ __launch_bounds__(256) void k_scanatt(
        const float* __restrict__ lapdown, const float* __restrict__ lapup,
        const float* __restrict__ stP,
        int* __restrict__ cntbuf, int* __restrict__ colbuf,
        float* __restrict__ valbuf) {
    __shared__ int colsh[4][CAP];            // per-wave col stash (avoids RAW)
    int sel = blockIdx.y;
    const float* lap = sel ? lapup : lapdown;
    int wid = threadIdx.x >> 6;
    int row = (int)blockIdx.x * 4 + wid;
    int lane = threadIdx.x & 63;
    const float4* lr = (const float4*)(lap + (size_t)row * NN);
    int* crow = colbuf + (size_t)sel * NN * CAP + (size_t)row * CAP;
    int* csh = colsh[wid];
    unsigned long long ltmask = (1ull << lane) - 1ull;
    int c = 0;
    float4 buf[8];
#pragma unroll
    for (int j = 0; j < 8; ++j) buf[j] = lr[j * 64 + lane];   // 8 loads in flight
    for (int t = 0; t < 32; t += 8) {
        float4 nbuf[8];
        if (t + 8 < 32) {
#pragma unroll
            for (int j = 0; j < 8; ++j) nbuf[j] = lr[(t + 8 + j) * 64 + lane];
        }
#pragma unroll
        for (int j = 0; j < 8; ++j) {
            int it = t + j;
            float4 v = buf[j];
#pragma unroll
            for (int q = 0; q < 4; ++q) {
                float f = (q == 0) ? v.x : (q == 1) ? v.y : (q == 2) ? v.z : v.w;
                bool nz = (f != 0.0f);
                unsigned long long m = __ballot(nz);
                if (nz) {
                    int slot = c + __popcll(m & ltmask);
                    if (slot < CAP) {
                        int cidx = it * 256 + lane * 4 + q;
                        crow[slot] = cidx;
                        csh[slot] = cidx;
                    }
                }
                c += __popcll(m);
            }
        }
#pragma unroll
        for (int j = 0; j < 8; ++j) buf[j] = nbuf[j];
    }
    int cc = (c < CAP) ? c : CAP;
    int cpad = (cc + 15) & ~15;
    if (cpad > CAP) cpad = CAP;
    if (lane < cpad - cc) crow[cc + lane] = 0;      // pad col -> row 0 (val 0)
    if (lane == 0) cntbuf[sel * NN + row] = cc;
    // --------- softmax over the cc edges of this row (s,t = sum of f-halves)
    const float* sP0 = stP + (size_t)(2 * sel) * NN;
    const float* sP1 = sP0 + NN;
    const float* tP0 = stP + (size_t)(4 + 2 * sel) * NN;
    const float* tP1 = tP0 + NN;
    float* vr = valbuf + (size_t)sel * NN * CAP + (size_t)row * CAP;
    float tv = tP0[row] + tP1[row];
    float e0 = -1e30f, e1 = -1e30f;
    if (lane < cc) {
        int j = csh[lane];
        float v = tv + sP0[j] + sP1[j];
        e0 = v > 0.f ? v : expm1f(v);
    }
    if (lane + 64 < cc) {
        int j = csh[lane + 64];
        float v = tv + sP0[j] + sP1[j];
        e1 = v > 0.f ? v : expm1f(v);
    }
    float m = fmaxf(e0, e1);
    for (int off = 32; off; off >>= 1) m = fmaxf(m, __shfl_xor(m, off));
    float p0 = (lane < cc)      ? expf(e0 - m) : 0.f;
    float p1 = (lane + 64 < cc) ? expf(e1 - m) : 0.f;
    float sum = p0 + p1;
    for (int off = 32; off; off >>= 1) sum += __shfl_xor(sum, off);
    float inv = 1.0f / sum;
    if (lane < cc)      vr[lane] = p0 * inv;
    if (lane + 64 < cc) vr[lane + 64] = p1 * inv;
    if (lane < cpad - cc) vr[cc + lane] = 0.f;      // zero the pad slots
}

// ---------------------------------- h (8192x128 f32) -> hT (128x8192 bf16)
__global__ __launch_bounds__(512) void k_tr(
        const float* __restrict__ h, unsigned short* __restrict__ hT) {
    __shared__ unsigned short tile[32 * 128];
    int tid = threadIdx.x;
    int k0 = blockIdx.x * 32;
    int r = tid >> 4;
    int c0 = (tid & 15) * 8;
    const float4* src = (const float4*)(h + (size_t)(k0 + r) * 128 + c0);
    float4 a = src[0], b = src[1];
    unsigned short* tp = &tile[r * 128 + c0];
    tp[0] = (unsigned short)f2bf(a.x); tp[1] = (unsigned short)f2bf(a.y);
    tp[2] = (unsigned short)f2bf(a.z); tp[3] = (unsigned short)f2bf(a.w);
    tp[4] = (unsigned short)f2bf(b.x); tp[5] = (unsigned short)f2bf(b.y);
    tp[6] = (unsigned short)f2bf(b.z); tp[7] = (unsigned short)f2bf(b.w);
    __syncthreads();
    int c = tid & 127;
    int seg = tid >> 7;
    unsigned short v[8];
#pragma unroll
    for (int i = 0; i < 8; ++i) v[i] = tile[(seg * 8 + i) * 128 + c];
    uint4 pack;
    pack.x = (unsigned)v[0] | ((unsigned)v[1] << 16);
    pack.y = (unsigned)v[2] | ((unsigned)v[3] << 16);
    pack.z = (unsigned)v[4] | ((unsigned)v[5] << 16);
    pack.w = (unsigned)v[6] | ((unsigned)v[7] << 16);
    *(uint4*)(hT + (size_t)c * NN + k0 + seg * 8) = pack;
}

// ---- z_har partials = proj @ h : LDS double-buffered, reg-staged pipeline
__global__ __launch_bounds__(256) void k_proj(
        const float* __restrict__ P, const unsigned short* __restrict__ hT,
        float* __restrict__ partial) {
    __shared__ float As[2][64 * PLDA];
    __shared__ unsigned short Bs[2][128 * PLDB];
    int tid = threadIdx.x;
    int strip = (int)blockIdx.x >> 2;
    int ks = (int)blockIdx.x & 3;
    int RB = strip * 64;
    int k0 = ks * 2048;
    int w = tid >> 6, lane = tid & 63;
    int l15 = lane & 15, koff = (lane >> 4) * 8;
    int ar = tid >> 2, ak = (tid & 3) * 16;
    int bn = tid >> 1, bk = (tid & 1) * 32;
    const float* Ag = P + (size_t)(RB + ar) * NN + k0 + ak;
    const unsigned short* Bg = hT + (size_t)bn * NN + k0 + bk;
    float* Aw0 = &As[0][ar * PLDA + ak];
    unsigned short* Bw0 = &Bs[0][bn * PLDB + bk];
    float* Aw1 = &As[1][ar * PLDA + ak];
    unsigned short* Bw1 = &Bs[1][bn * PLDB + bk];

    float4 sa[4]; uint4 sb[4];
#pragma unroll
    for (int i = 0; i < 4; ++i) sa[i] = *(const float4*)(Ag + i * 4);
#pragma unroll
    for (int i = 0; i < 4; ++i) sb[i] = *(const uint4*)(Bg + i * 8);
#pragma unroll
    for (int i = 0; i < 4; ++i) *(float4*)(Aw0 + i * 4) = sa[i];
#pragma unroll
    for (int i = 0; i < 4; ++i) *(uint4*)(Bw0 + i * 8) = sb[i];
    __syncthreads();

    f32x4 acc[8];
#pragma unroll
    for (int i = 0; i < 8; ++i) acc[i] = (f32x4){0.f, 0.f, 0.f, 0.f};

    for (int t = 0; t < 32; ++t) {
        int cur = t & 1;
        if (t + 1 < 32) {
            const float* Agn = Ag + (t + 1) * 64;
            const unsigned short* Bgn = Bg + (t + 1) * 64;
#pragma unroll
            for (int i = 0; i < 4; ++i) sa[i] = *(const float4*)(Agn + i * 4);
#pragma unroll
            for (int i = 0; i < 4; ++i) sb[i] = *(const uint4*)(Bgn + i * 8);
        }
#pragma unroll
        for (int kk = 0; kk < 2; ++kk) {
            const float* Ab = &As[cur][(w * 16 + l15) * PLDA + kk * 32 + koff];
            float4 a0 = *(const float4*)Ab;
            float4 a1 = *(const float4*)(Ab + 4);
            bf16x8 af;
            af[0] = f2bf(a0.x); af[1] = f2bf(a0.y); af[2] = f2bf(a0.z); af[3] = f2bf(a0.w);
            af[4] = f2bf(a1.x); af[5] = f2bf(a1.y); af[6] = f2bf(a1.z); af[7] = f2bf(a1.w);
#pragma unroll
            for (int ct = 0; ct < 8; ++ct) {
                bf16x8 bf = *(const bf16x8*)(&Bs[cur][(ct * 16 + l15) * PLDB + kk * 32 + koff]);
                acc[ct] = __builtin_amdgcn_mfma_f32_16x16x32_bf16(af, bf, acc[ct], 0, 0, 0);
            }
        }
        if (t + 1 < 32) {
            float* Aw = (cur ? Aw0 : Aw1);
            unsigned short* Bw = (cur ? Bw0 : Bw1);
#pragma unroll
            for (int i = 0; i < 4; ++i) *(float4*)(Aw + i * 4) = sa[i];
#pragma unroll
            for (int i = 0; i < 4; ++i) *(uint4*)(Bw + i * 8) = sb[i];
        }
        __syncthreads();
    }
    float* out = partial + (size_t)ks * NN * 128;
    int prow = RB + w * 16 + (lane >> 4) * 4;
#pragma unroll
    for (int ct = 0; ct < 8; ++ct)
#pragma unroll
        for (int r = 0; r < 4; ++r)
            out[(size_t)(prow + r) * 128 + ct * 16 + l15] = acc[ct][r];
}

// ------- 16-edge gather block: 16 loads in flight, 2 independent acc pairs
__device__ __forceinline__ void gather16(
        const int* __restrict__ cr, const float* __restrict__ vr,
        const float* __restrict__ B, int lane,
        float& ax0, float& ay0, float& ax1, float& ay1) {
#pragma unroll
    for (int h = 0; h < 2; ++h) {
        int4   ja = *(const int4*)(cr + h * 8);
        int4   jb = *(const int4*)(cr + h * 8 + 4);
        float4 va = *(const float4*)(vr + h * 8);
        float4 vb = *(const float4*)(vr + h * 8 + 4);
        float2 b0 = ((const float2*)(B + (size_t)ja.x * 128))[lane];
        float2 b1 = ((const float2*)(B + (size_t)ja.y * 128))[lane];
        float2 b2 = ((const float2*)(B + (size_t)ja.z * 128))[lane];
        float2 b3 = ((const float2*)(B + (size_t)ja.w * 128))[lane];
        float2 b4 = ((const float2*)(B + (size_t)jb.x * 128))[lane];
        float2 b5 = ((const float2*)(B + (size_t)jb.y * 128))[lane];
        float2 b6 = ((const float2*)(B + (size_t)jb.z * 128))[lane];
        float2 b7 = ((const float2*)(B + (size_t)jb.w * 128))[lane];
        ax0 += va.x * b0.x; ay0 += va.x * b0.y;
        ax1 += va.y * b1.x; ay1 += va.y * b1.y;
        ax0 += va.z * b2.x; ay0 += va.z * b2.y;
        ax1 += va.w * b3.x; ay1 += va.w * b3.y;
        ax0 += vb.x * b4.x; ay0 += vb.x * b4.y;
        ax1 += vb.y * b5.x; ay1 += vb.y * b5.y;
        ax0 += vb.z * b6.x; ay0 += vb.z * b6.y;
        ax1 += vb.w * b7.x; ay1 += vb.w * b7.y;
    }
}

// ----- pass 1 (both convs per wave): w_sel[row] = z_sel0[row] + A_sel @ z_sel1
__global__ __launch_bounds__(256) void k_pass1(
        const int* __restrict__ cnt, const int* __restrict__ col,
        const float* __restrict__ val, const float* __restrict__ zbuf,
        float* __restrict__ wbuf) {
    int row = ((int)blockIdx.x * 256 + (int)threadIdx.x) >> 6;
    int lane = threadIdx.x & 63;
    const size_t ZS = (size_t)NN * 128;
    int cD = cnt[row], cU = cnt[NN + row];
    int padD = (cD + 15) & ~15, padU = (cU + 15) & ~15;
    const int*   crD = col + (size_t)row * CAP;
    const int*   crU = col + ((size_t)NN + row) * CAP;
    const float* vrD = val + (size_t)row * CAP;
    const float* vrU = val + ((size_t)NN + row) * CAP;
    float2 iD = ((const float2*)(zbuf + (size_t)row * 128))[lane];            // z_d0
    float2 iU = ((const float2*)(zbuf + 2 * ZS + (size_t)row * 128))[lane];   // z_u0
    float axD0 = iD.x, ayD0 = iD.y, axD1 = 0.f, ayD1 = 0.f;
    float axU0 = iU.x, ayU0 = iU.y, axU1 = 0.f, ayU1 = 0.f;
    int emax = padD > padU ? padD : padU;
    for (int e = 0; e < emax; e += 16) {
        if (e < padD)
            gather16(crD + e, vrD + e, zbuf + ZS, lane, axD0, ayD0, axD1, ayD1);
        if (e < padU)
            gather16(crU + e, vrU + e, zbuf + 3 * ZS, lane, axU0, ayU0, axU1, ayU1);
    }
    ((float2*)(wbuf + (size_t)row * 128))[lane] = make_float2(axD0 + axD1, ayD0 + ayD1);
    ((float2*)(wbuf + ZS + (size_t)row * 128))[lane] = make_float2(axU0 + axU1, ayU0 + ayU1);
}

// ---------- final: out = sum_ks partial + A_d @ w_d + A_u @ w_u
__global__ __launch_bounds__(256) void k_final(
        const int* __restrict__ cnt, const int* __restrict__ col,
        const float* __restrict__ val, const float* __restrict__ wbuf,
        const float* __restrict__ partial, float* __restrict__ out) {
    int row = ((int)blockIdx.x * 256 + (int)threadIdx.x) >> 6;
    int lane = threadIdx.x & 63;
    const size_t ZS = (size_t)NN * 128;
    float ax0 = 0.f, ay0 = 0.f, ax1 = 0.f, ay1 = 0.f;
#pragma unroll
    for (int ks = 0; ks < 4; ks += 2) {
        float2 p0 = ((const float2*)(partial + (size_t)ks * ZS + (size_t)row * 128))[lane];
        float2 p1 = ((const float2*)(partial + (size_t)(ks + 1) * ZS + (size_t)row * 128))[lane];
        ax0 += p0.x; ay0 += p0.y; ax1 += p1.x; ay1 += p1.y;
    }
    int cD = cnt[row], cU = cnt[NN + row];
    int padD = (cD + 15) & ~15, padU = (cU + 15) & ~15;
    const int*   crD = col + (size_t)row * CAP;
    const int*   crU = col + ((size_t)NN + row) * CAP;
    const float* vrD = val + (size_t)row * CAP;
    const float* vrU = val + ((size_t)NN + row) * CAP;
    int emax = padD > padU ? padD : padU;
    for (int e = 0; e < emax; e += 16) {
        if (e < padD)
            gather16(crD + e, vrD + e, wbuf, lane, ax0, ay0, ax1, ay1);
        if (e < padU)
            gather16(crU + e, vrU + e, wbuf + ZS, lane, ax0, ay0, ax1, ay1);
    }
    ((float2*)(out + (size_t)row * 128))[lane] = make_float2(ax0 + ax1, ay0 + ay1);
}

extern "C" void kernel_launch(void* const* d_in, const int* in_sizes, int n_in,
                              void* d_out, int out_size, void* d_ws, size_t ws_size,
                              hipStream_t stream) {
    const float* x        = (const float*)d_in[0];
    const float* lap_up   = (const float*)d_in[1];
    const float* lap_down = (const float*)d_in[2];
    const float* proj     = (const float*)d_in[3];
    const float* W_up     = (const float*)d_in[4];
    const float* a_up     = (const float*)d_in[5];
    const float* W_down   = (const float*)d_in[6];
    const float* a_down   = (const float*)d_in[7];
    const float* W_har    = (const float*)d_in[8];
    float* out = (float*)d_out;
    float* ws = (float*)d_ws;

    const size_t ZSZ = (size_t)NN * 128;      // 1,048,576 floats
    size_t off = 0;
    float* zbuf = ws + off;              off += 5 * ZSZ;   // z_d0,z_d1,z_u0,z_u1,h
    float* stbuf = ws + off;             off += 8 * NN;    // sP[4],tP[4]
    int* cntbuf = (int*)(ws + off);      off += 2 * NN;
    int* colbuf = (int*)(ws + off);      off += 2 * ZSZ;
    float* valbuf = ws + off;            off += 2 * ZSZ;
    float* wbuf = ws + off;              off += 2 * ZSZ;   // w_d, w_u
    unsigned short* hT = (unsigned short*)(ws + off); off += ZSZ / 2;
    float* partial = ws + off;           off += 4 * ZSZ;   // ~65 MB total

    hipLaunchKernelGGL(k_small_gemm, dim3(256, 5), dim3(256), 0, stream,
                       x, W_down, W_up, W_har, a_down, a_up, zbuf, stbuf);
    hipLaunchKernelGGL(k_scanatt, dim3(2048, 2), dim3(256), 0, stream,
                       lap_down, lap_up, stbuf, cntbuf, colbuf, valbuf);
    hipLaunchKernelGGL(k_tr, dim3(256), dim3(512), 0, stream,
                       zbuf + 4 * ZSZ, hT);
    hipLaunchKernelGGL(k_proj, dim3(512), dim3(256), 0, stream,
                       proj, hT, partial);
    hipLaunchKernelGGL(k_pass1, dim3(2048), dim3(256), 0, stream,
                       cntbuf, colbuf, valbuf, zbuf, wbuf);
    hipLaunchKernelGGL(k_final, dim3(2048), dim3(256), 0, stream,
                       cntbuf, colbuf, valbuf, wbuf, partial, out);
}

// Round 11
// 820.077 us; speedup vs baseline: 1.0182x; 1.0182x over previous
//
#include <hip/hip_runtime.h>

#define NN 8192
#define CAP 128          // max nnz per Laplacian row (mean ~34, P(>128) ~ 0)
#define PLDA 68          // A LDS row stride (64+4 floats)
#define PLDB 72          // B LDS row stride (64+8 shorts)

typedef __attribute__((ext_vector_type(8))) short bf16x8;
typedef __attribute__((ext_vector_type(4))) float f32x4;

__device__ __forceinline__ short f2bf(float f) {
    unsigned u = __builtin_bit_cast(unsigned, f);
    u += 0x7FFFu + ((u >> 16) & 1u);          // round-to-nearest-even
    return (short)(u >> 16);
}

// ---------------- z = x @ W  (+ fused partial s,t for the attention convs)
// stP layout: sP[4][NN] then tP[4][NN]; wsel 0..3 = down_f0,down_f1,up_f0,up_f1
__global__ __launch_bounds__(256) void k_small_gemm(
        const float* __restrict__ x, const float* __restrict__ Wdown,
        const float* __restrict__ Wup, const float* __restrict__ Whar,
        const float* __restrict__ a_down, const float* __restrict__ a_up,
        float* __restrict__ zbuf, float* __restrict__ stP) {
    int wsel = blockIdx.y;
    const float* W = (wsel == 0) ? Wdown : (wsel == 1) ? Wdown + 16384 :
                     (wsel == 2) ? Wup   : (wsel == 3) ? Wup + 16384 : Whar;
    float* out = zbuf + (size_t)wsel * NN * 128;
    __shared__ float Wl[128 * 128];
    __shared__ float Xl[32 * 128];
    int tid = threadIdx.x;
    int row0 = blockIdx.x * 32;
    const float4* W4 = (const float4*)W;
    float4* Wl4 = (float4*)Wl;
    for (int i = tid; i < 4096; i += 256) Wl4[i] = W4[i];
    const float4* X4 = (const float4*)(x + (size_t)row0 * 128);
    float4* Xl4 = (float4*)Xl;
    for (int i = tid; i < 1024; i += 256) Xl4[i] = X4[i];
    __syncthreads();
    int tx = tid & 31, ty = tid >> 5;
    float acc[4][4] = {};
#pragma unroll 2
    for (int i = 0; i < 128; ++i) {
        float w0 = Wl[i * 128 + tx];
        float w1 = Wl[i * 128 + tx + 32];
        float w2 = Wl[i * 128 + tx + 64];
        float w3 = Wl[i * 128 + tx + 96];
#pragma unroll
        for (int rr = 0; rr < 4; ++rr) {
            float xv = Xl[(ty * 4 + rr) * 128 + i];
            acc[rr][0] += xv * w0; acc[rr][1] += xv * w1;
            acc[rr][2] += xv * w2; acc[rr][3] += xv * w3;
        }
    }
#pragma unroll
    for (int rr = 0; rr < 4; ++rr) {
        float* o = out + (size_t)(row0 + ty * 4 + rr) * 128 + tx;
        o[0] = acc[rr][0]; o[32] = acc[rr][1]; o[64] = acc[rr][2]; o[96] = acc[rr][3];
    }
    if (wsel < 4) {
        const float* a = (wsel < 2) ? a_down : a_up;
        int f = wsel & 1;
        float asv[4], atv[4];
#pragma unroll
        for (int q = 0; q < 4; ++q) {
            asv[q] = a[f * 128 + tx + q * 32];
            atv[q] = a[256 + f * 128 + tx + q * 32];
        }
#pragma unroll
        for (int rr = 0; rr < 4; ++rr) {
            float ps = acc[rr][0] * asv[0] + acc[rr][1] * asv[1]
                     + acc[rr][2] * asv[2] + acc[rr][3] * asv[3];
            float pt = acc[rr][0] * atv[0] + acc[rr][1] * atv[1]
                     + acc[rr][2] * atv[2] + acc[rr][3] * atv[3];
            for (int w = 16; w; w >>= 1) {
                ps += __shfl_xor(ps, w);
                pt += __shfl_xor(pt, w);
            }
            if (tx == 0) {
                int row = row0 + ty * 4 + rr;
                stP[(size_t)wsel * NN + row] = ps;
                stP[(size_t)(4 + wsel) * NN + row] = pt;
            }
        }
    }
}

// ---- fused: branchless bitmask scan -> padded CSR + elu-softmax weights
// per lane: private 128-bit presence mask (no ballots/branches in hot loop),
// then one wave scan + sparse emission (edge order is lane-major: valid,
// since col/val pairs stay consistent and the SpMM sum is commutative).
__global__ __launch_bounds__(256) void k_scanatt(
        const float* __restrict__ lapdown, const float* __restrict__ lapup,
        const float* __restrict__ stP,
        int* __restrict__ cntbuf, int* __restrict__ colbuf,
        float* __restrict__ valbuf) {
    __shared__ int colsh[4][CAP];            // per-wave col stash
    int sel = blockIdx.y;
    const float* lap = sel ? lapup : lapdown;
    int wid = threadIdx.x >> 6;
    int row = (int)blockIdx.x * 4 + wid;
    int lane = threadIdx.x & 63;
    const float4* lr = (const float4*)(lap + (size_t)row * NN);

    // hot loop: 4 chunks x 8 float4; all shifts compile-time constant
    unsigned mw0 = 0u, mw1 = 0u, mw2 = 0u, mw3 = 0u;
#pragma unroll
    for (int ch = 0; ch < 4; ++ch) {
        unsigned mw = 0u;
#pragma unroll
        for (int j = 0; j < 8; ++j) {
            float4 v = lr[(ch * 8 + j) * 64 + lane];
            mw |= (unsigned)(v.x != 0.f) << (j * 4 + 0);
            mw |= (unsigned)(v.y != 0.f) << (j * 4 + 1);
            mw |= (unsigned)(v.z != 0.f) << (j * 4 + 2);
            mw |= (unsigned)(v.w != 0.f) << (j * 4 + 3);
        }
        if (ch == 0) mw0 = mw; else if (ch == 1) mw1 = mw;
        else if (ch == 2) mw2 = mw; else mw3 = mw;
    }
    unsigned long long m0 = (unsigned long long)mw0 | ((unsigned long long)mw1 << 32);
    unsigned long long m1 = (unsigned long long)mw2 | ((unsigned long long)mw3 << 32);
    int nl = __popcll(m0) + __popcll(m1);

    // exclusive wave scan of per-lane counts
    int pre = nl;
#pragma unroll
    for (int off = 1; off < 64; off <<= 1) {
        int t = __shfl_up(pre, off);
        if (lane >= off) pre += t;
    }
    int base = pre - nl;                     // exclusive prefix
    int ctot = __shfl(pre, 63);              // row total
    int cc = (ctot < CAP) ? ctot : CAP;

    int* crow = colbuf + (size_t)sel * NN * CAP + (size_t)row * CAP;
    int* csh = colsh[wid];
    // emit this lane's nonzero columns (elem e -> col (e>>2)*256 + lane*4 + (e&3))
    int b = base;
    unsigned long long mm = m0;
    while (mm) {
        int e = __builtin_ctzll(mm);
        mm &= mm - 1;
        int col = ((e >> 2) << 8) + lane * 4 + (e & 3);
        if (b < CAP) { crow[b] = col; csh[b] = col; }
        ++b;
    }
    mm = m1;
    while (mm) {
        int e = __builtin_ctzll(mm) + 64;
        mm &= mm - 1;
        int col = ((e >> 2) << 8) + lane * 4 + (e & 3);
        if (b < CAP) { crow[b] = col; csh[b] = col; }
        ++b;
    }
    int cpad = (cc + 15) & ~15;
    if (cpad > CAP) cpad = CAP;
    if (lane < cpad - cc) crow[cc + lane] = 0;      // pad col -> row 0 (val 0)
    if (lane == 0) cntbuf[sel * NN + row] = cc;

    // --------- softmax over the cc edges of this row (s,t = sum of f-halves)
    const float* sP0 = stP + (size_t)(2 * sel) * NN;
    const float* sP1 = sP0 + NN;
    const float* tP0 = stP + (size_t)(4 + 2 * sel) * NN;
    const float* tP1 = tP0 + NN;
    float* vr = valbuf + (size_t)sel * NN * CAP + (size_t)row * CAP;
    float tv = tP0[row] + tP1[row];
    float e0 = -1e30f, e1 = -1e30f;
    if (lane < cc) {
        int j = csh[lane];
        float v = tv + sP0[j] + sP1[j];
        e0 = v > 0.f ? v : expm1f(v);
    }
    if (lane + 64 < cc) {
        int j = csh[lane + 64];
        float v = tv + sP0[j] + sP1[j];
        e1 = v > 0.f ? v : expm1f(v);
    }
    float m = fmaxf(e0, e1);
    for (int off = 32; off; off >>= 1) m = fmaxf(m, __shfl_xor(m, off));
    float p0 = (lane < cc)      ? expf(e0 - m) : 0.f;
    float p1 = (lane + 64 < cc) ? expf(e1 - m) : 0.f;
    float sum = p0 + p1;
    for (int off = 32; off; off >>= 1) sum += __shfl_xor(sum, off);
    float inv = 1.0f / sum;
    if (lane < cc)      vr[lane] = p0 * inv;
    if (lane + 64 < cc) vr[lane + 64] = p1 * inv;
    if (lane < cpad - cc) vr[cc + lane] = 0.f;      // zero the pad slots
}

// ---------------------------------- h (8192x128 f32) -> hT (128x8192 bf16)
__global__ __launch_bounds__(512) void k_tr(
        const float* __restrict__ h, unsigned short* __restrict__ hT) {
    __shared__ unsigned short tile[32 * 128];
    int tid = threadIdx.x;
    int k0 = blockIdx.x * 32;
    int r = tid >> 4;
    int c0 = (tid & 15) * 8;
    const float4* src = (const float4*)(h + (size_t)(k0 + r) * 128 + c0);
    float4 a = src[0], b = src[1];
    unsigned short* tp = &tile[r * 128 + c0];
    tp[0] = (unsigned short)f2bf(a.x); tp[1] = (unsigned short)f2bf(a.y);
    tp[2] = (unsigned short)f2bf(a.z); tp[3] = (unsigned short)f2bf(a.w);
    tp[4] = (unsigned short)f2bf(b.x); tp[5] = (unsigned short)f2bf(b.y);
    tp[6] = (unsigned short)f2bf(b.z); tp[7] = (unsigned short)f2bf(b.w);
    __syncthreads();
    int c = tid & 127;
    int seg = tid >> 7;
    unsigned short v[8];
#pragma unroll
    for (int i = 0; i < 8; ++i) v[i] = tile[(seg * 8 + i) * 128 + c];
    uint4 pack;
    pack.x = (unsigned)v[0] | ((unsigned)v[1] << 16);
    pack.y = (unsigned)v[2] | ((unsigned)v[3] << 16);
    pack.z = (unsigned)v[4] | ((unsigned)v[5] << 16);
    pack.w = (unsigned)v[6] | ((unsigned)v[7] << 16);
    *(uint4*)(hT + (size_t)c * NN + k0 + seg * 8) = pack;
}

// ---- z_har partials = proj @ h : LDS double-buffered, reg-staged pipeline
__global__ __launch_bounds__(256) void k_proj(
        const float* __restrict__ P, const unsigned short* __restrict__ hT,
        float* __restrict__ partial) {
    __shared__ float As[2][64 * PLDA];
    __shared__ unsigned short Bs[2][128 * PLDB];
    int tid = threadIdx.x;
    int strip = (int)blockIdx.x >> 2;
    int ks = (int)blockIdx.x & 3;
    int RB = strip * 64;
    int k0 = ks * 2048;
    int w = tid >> 6, lane = tid & 63;
    int l15 = lane & 15, koff = (lane >> 4) * 8;
    int ar = tid >> 2, ak = (tid & 3) * 16;
    int bn = tid >> 1, bk = (tid & 1) * 32;
    const float* Ag = P + (size_t)(RB + ar) * NN + k0 + ak;
    const unsigned short* Bg = hT + (size_t)bn * NN + k0 + bk;
    float* Aw0 = &As[0][ar * PLDA + ak];
    unsigned short* Bw0 = &Bs[0][bn * PLDB + bk];
    float* Aw1 = &As[1][ar * PLDA + ak];
    unsigned short* Bw1 = &Bs[1][bn * PLDB + bk];

    float4 sa[4]; uint4 sb[4];
#pragma unroll
    for (int i = 0; i < 4; ++i) sa[i] = *(const float4*)(Ag + i * 4);
#pragma unroll
    for (int i = 0; i < 4; ++i) sb[i] = *(const uint4*)(Bg + i * 8);
#pragma unroll
    for (int i = 0; i < 4; ++i) *(float4*)(Aw0 + i * 4) = sa[i];
#pragma unroll
    for (int i = 0; i < 4; ++i) *(uint4*)(Bw0 + i * 8) = sb[i];
    __syncthreads();

    f32x4 acc[8];
#pragma unroll
    for (int i = 0; i < 8; ++i) acc[i] = (f32x4){0.f, 0.f, 0.f, 0.f};

    for (int t = 0; t < 32; ++t) {
        int cur = t & 1;
        if (t + 1 < 32) {
            const float* Agn = Ag + (t + 1) * 64;
            const unsigned short* Bgn = Bg + (t + 1) * 64;
#pragma unroll
            for (int i = 0; i < 4; ++i) sa[i] = *(const float4*)(Agn + i * 4);
#pragma unroll
            for (int i = 0; i < 4; ++i) sb[i] = *(const uint4*)(Bgn + i * 8);
        }
#pragma unroll
        for (int kk = 0; kk < 2; ++kk) {
            const float* Ab = &As[cur][(w * 16 + l15) * PLDA + kk * 32 + koff];
            float4 a0 = *(const float4*)Ab;
            float4 a1 = *(const float4*)(Ab + 4);
            bf16x8 af;
            af[0] = f2bf(a0.x); af[1] = f2bf(a0.y); af[2] = f2bf(a0.z); af[3] = f2bf(a0.w);
            af[4] = f2bf(a1.x); af[5] = f2bf(a1.y); af[6] = f2bf(a1.z); af[7] = f2bf(a1.w);
#pragma unroll
            for (int ct = 0; ct < 8; ++ct) {
                bf16x8 bf = *(const bf16x8*)(&Bs[cur][(ct * 16 + l15) * PLDB + kk * 32 + koff]);
                acc[ct] = __builtin_amdgcn_mfma_f32_16x16x32_bf16(af, bf, acc[ct], 0, 0, 0);
            }
        }
        if (t + 1 < 32) {
            float* Aw = (cur ? Aw0 : Aw1);
            unsigned short* Bw = (cur ? Bw0 : Bw1);
#pragma unroll
            for (int i = 0; i < 4; ++i) *(float4*)(Aw + i * 4) = sa[i];
#pragma unroll
            for (int i = 0; i < 4; ++i) *(uint4*)(Bw + i * 8) = sb[i];
        }
        __syncthreads();
    }
    float* out = partial + (size_t)ks * NN * 128;
    int prow = RB + w * 16 + (lane >> 4) * 4;
#pragma unroll
    for (int ct = 0; ct < 8; ++ct)
#pragma unroll
        for (int r = 0; r < 4; ++r)
            out[(size_t)(prow + r) * 128 + ct * 16 + l15] = acc[ct][r];
}

// ------- 16-edge gather block: 16 loads in flight, 2 independent acc pairs
__device__ __forceinline__ void gather16(
        const int* __restrict__ cr, const float* __restrict__ vr,
        const float* __restrict__ B, int lane,
        float& ax0, float& ay0, float& ax1, float& ay1) {
#pragma unroll
    for (int h = 0; h < 2; ++h) {
        int4   ja = *(const int4*)(cr + h * 8);
        int4   jb = *(const int4*)(cr + h * 8 + 4);
        float4 va = *(const float4*)(vr + h * 8);
        float4 vb = *(const float4*)(vr + h * 8 + 4);
        float2 b0 = ((const float2*)(B + (size_t)ja.x * 128))[lane];
        float2 b1 = ((const float2*)(B + (size_t)ja.y * 128))[lane];
        float2 b2 = ((const float2*)(B + (size_t)ja.z * 128))[lane];
        float2 b3 = ((const float2*)(B + (size_t)ja.w * 128))[lane];
        float2 b4 = ((const float2*)(B + (size_t)jb.x * 128))[lane];
        float2 b5 = ((const float2*)(B + (size_t)jb.y * 128))[lane];
        float2 b6 = ((const float2*)(B + (size_t)jb.z * 128))[lane];
        float2 b7 = ((const float2*)(B + (size_t)jb.w * 128))[lane];
        ax0 += va.x * b0.x; ay0 += va.x * b0.y;
        ax1 += va.y * b1.x; ay1 += va.y * b1.y;
        ax0 += va.z * b2.x; ay0 += va.z * b2.y;
        ax1 += va.w * b3.x; ay1 += va.w * b3.y;
        ax0 += vb.x * b4.x; ay0 += vb.x * b4.y;
        ax1 += vb.y * b5.x; ay1 += vb.y * b5.y;
        ax0 += vb.z * b6.x; ay0 += vb.z * b6.y;
        ax1 += vb.w * b7.x; ay1 += vb.w * b7.y;
    }
}

// ----- pass 1 (both convs per wave): w_sel[row] = z_sel0[row] + A_sel @ z_sel1
__global__ __launch_bounds__(256) void k_pass1(
        const int* __restrict__ cnt, const int* __restrict__ col,
        const float* __restrict__ val, const float* __restrict__ zbuf,
        float* __restrict__ wbuf) {
    int row = ((int)blockIdx.x * 256 + (int)threadIdx.x) >> 6;
    int lane = threadIdx.x & 63;
    const size_t ZS = (size_t)NN * 128;
    int cD = cnt[row], cU = cnt[NN + row];
    int padD = (cD + 15) & ~15, padU = (cU + 15) & ~15;
    const int*   crD = col + (size_t)row * CAP;
    const int*   crU = col + ((size_t)NN + row) * CAP;
    const float* vrD = val + (size_t)row * CAP;
    const float* vrU = val + ((size_t)NN + row) * CAP;
    float2 iD = ((const float2*)(zbuf + (size_t)row * 128))[lane];            // z_d0
    float2 iU = ((const float2*)(zbuf + 2 * ZS + (size_t)row * 128))[lane];   // z_u0
    float axD0 = iD.x, ayD0 = iD.y, axD1 = 0.f, ayD1 = 0.f;
    float axU0 = iU.x, ayU0 = iU.y, axU1 = 0.f, ayU1 = 0.f;
    int emax = padD > padU ? padD : padU;
    for (int e = 0; e < emax; e += 16) {
        if (e < padD)
            gather16(crD + e, vrD + e, zbuf + ZS, lane, axD0, ayD0, axD1, ayD1);
        if (e < padU)
            gather16(crU + e, vrU + e, zbuf + 3 * ZS, lane, axU0, ayU0, axU1, ayU1);
    }
    ((float2*)(wbuf + (size_t)row * 128))[lane] = make_float2(axD0 + axD1, ayD0 + ayD1);
    ((float2*)(wbuf + ZS + (size_t)row * 128))[lane] = make_float2(axU0 + axU1, ayU0 + ayU1);
}

// ---------- final: out = sum_ks partial + A_d @ w_d + A_u @ w_u
__global__ __launch_bounds__(256) void k_final(
        const int* __restrict__ cnt, const int* __restrict__ col,
        const float* __restrict__ val, const float* __restrict__ wbuf,
        const float* __restrict__ partial, float* __restrict__ out) {
    int row = ((int)blockIdx.x * 256 + (int)threadIdx.x) >> 6;
    int lane = threadIdx.x & 63;
    const size_t ZS = (size_t)NN * 128;
    float ax0 = 0.f, ay0 = 0.f, ax1 = 0.f, ay1 = 0.f;
#pragma unroll
    for (int ks = 0; ks < 4; ks += 2) {
        float2 p0 = ((const float2*)(partial + (size_t)ks * ZS + (size_t)row * 128))[lane];
        float2 p1 = ((const float2*)(partial + (size_t)(ks + 1) * ZS + (size_t)row * 128))[lane];
        ax0 += p0.x; ay0 += p0.y; ax1 += p1.x; ay1 += p1.y;
    }
    int cD = cnt[row], cU = cnt[NN + row];
    int padD = (cD + 15) & ~15, padU = (cU + 15) & ~15;
    const int*   crD = col + (size_t)row * CAP;
    const int*   crU = col + ((size_t)NN + row) * CAP;
    const float* vrD = val + (size_t)row * CAP;
    const float* vrU = val + ((size_t)NN + row) * CAP;
    int emax = padD > padU ? padD : padU;
    for (int e = 0; e < emax; e += 16) {
        if (e < padD)
            gather16(crD + e, vrD + e, wbuf, lane, ax0, ay0, ax1, ay1);
        if (e < padU)
            gather16(crU + e, vrU + e, wbuf + ZS, lane, ax0, ay0, ax1, ay1);
    }
    ((float2*)(out + (size_t)row * 128))[lane] = make_float2(ax0 + ax1, ay0 + ay1);
}

extern "C" void kernel_launch(void* const* d_in, const int* in_sizes, int n_in,
                              void* d_out, int out_size, void* d_ws, size_t ws_size,
                              hipStream_t stream) {
    const float* x        = (const float*)d_in[0];
    const float* lap_up   = (const float*)d_in[1];
    const float* lap_down = (const float*)d_in[2];
    const float* proj     = (const float*)d_in[3];
    const float* W_up     = (const float*)d_in[4];
    const float* a_up     = (const float*)d_in[5];
    const float* W_down   = (const float*)d_in[6];
    const float* a_down   = (const float*)d_in[7];
    const float* W_har    = (const float*)d_in[8];
    float* out = (float*)d_out;
    float* ws = (float*)d_ws;

    const size_t ZSZ = (size_t)NN * 128;      // 1,048,576 floats
    size_t off = 0;
    float* zbuf = ws + off;              off += 5 * ZSZ;   // z_d0,z_d1,z_u0,z_u1,h
    float* stbuf = ws + off;             off += 8 * NN;    // sP[4],tP[4]
    int* cntbuf = (int*)(ws + off);      off += 2 * NN;
    int* colbuf = (int*)(ws + off);      off += 2 * ZSZ;
    float* valbuf = ws + off;            off += 2 * ZSZ;
    float* wbuf = ws + off;              off += 2 * ZSZ;   // w_d, w_u
    unsigned short* hT = (unsigned short*)(ws + off); off += ZSZ / 2;
    float* partial = ws + off;           off += 4 * ZSZ;   // ~65 MB total

    hipLaunchKernelGGL(k_small_gemm, dim3(256, 5), dim3(256), 0, stream,
                       x, W_down, W_up, W_har, a_down, a_up, zbuf, stbuf);
    hipLaunchKernelGGL(k_scanatt, dim3(2048, 2), dim3(256), 0, stream,
                       lap_down, lap_up, stbuf, cntbuf, colbuf, valbuf);
    hipLaunchKernelGGL(k_tr, dim3(256), dim3(512), 0, stream,
                       zbuf + 4 * ZSZ, hT);
    hipLaunchKernelGGL(k_proj, dim3(512), dim3(256), 0, stream,
                       proj, hT, partial);
    hipLaunchKernelGGL(k_pass1, dim3(2048), dim3(256), 0, stream,
                       cntbuf, colbuf, valbuf, zbuf, wbuf);
    hipLaunchKernelGGL(k_final, dim3(2048), dim3(256), 0, stream,
                       cntbuf, colbuf, valbuf, wbuf, partial, out);
}